// Round 6
// baseline (806.969 us; speedup 1.0000x reference)
//
#include <hip/hip_runtime.h>

// Shapes (fixed by the problem)
#define BB 8
#define SS 2048
#define FF 1024
#define DD 512

typedef __attribute__((ext_vector_type(4))) float f32x4;
typedef __attribute__((ext_vector_type(8))) short s16x8;
typedef __attribute__((ext_vector_type(4))) short s16x4;

__device__ __forceinline__ unsigned short f2bf(float f) {
  unsigned int u = __builtin_bit_cast(unsigned int, f);
  unsigned int r = ((u >> 16) & 1u) + 0x7fffu;
  return (unsigned short)((u + r) >> 16);
}

__device__ __forceinline__ void async16(const void* g, void* l) {
  __builtin_amdgcn_global_load_lds((const __attribute__((address_space(1))) void*)g,
                                   (__attribute__((address_space(3))) void*)l, 16, 0, 0);
}

// ---------------------------------------------------------------------------
// Kernel 0: x fp32 -> bf16 (for MFMA) + passthrough copy into out[:, :1024]
// ---------------------------------------------------------------------------
__global__ __launch_bounds__(256) void convert_x(const float* __restrict__ x,
                                                 float* __restrict__ out,
                                                 unsigned short* __restrict__ xb) {
  size_t idx = ((size_t)blockIdx.x * 256 + threadIdx.x) * 4;
  f32x4 v = *(const f32x4*)(x + idx);
  size_t row = idx >> 10;
  size_t col = idx & 1023;
  *(f32x4*)(out + row * 1536 + col) = v;
  s16x4 h;
  h[0] = (short)f2bf(v[0]); h[1] = (short)f2bf(v[1]);
  h[2] = (short)f2bf(v[2]); h[3] = (short)f2bf(v[3]);
  *(s16x4*)(xb + idx) = h;
}

// ---------------------------------------------------------------------------
// Kernel 1: transpose+convert the 3 weights [1024][512] f32 -> Wt bf16 [512][1024]
// ---------------------------------------------------------------------------
__global__ __launch_bounds__(256) void prep_w(const float* __restrict__ Wq,
                                              const float* __restrict__ Wk,
                                              const float* __restrict__ Wv,
                                              unsigned short* __restrict__ wt) {
  int z = blockIdx.z;
  const float* W = (z == 0) ? Wq : ((z == 1) ? Wk : Wv);
  unsigned short* o = wt + (size_t)z * DD * FF;
  __shared__ __align__(16) float t[32][33];
  int k0 = blockIdx.x * 32, n0 = blockIdx.y * 32;
  int tid = threadIdx.x;
  int r = tid >> 3, c4 = (tid & 7) * 4;
  f32x4 v = *(const f32x4*)(W + (size_t)(k0 + r) * DD + n0 + c4);
  t[r][c4 + 0] = v[0]; t[r][c4 + 1] = v[1]; t[r][c4 + 2] = v[2]; t[r][c4 + 3] = v[3];
  __syncthreads();
  s16x4 h;
  h[0] = (short)f2bf(t[c4 + 0][r]);
  h[1] = (short)f2bf(t[c4 + 1][r]);
  h[2] = (short)f2bf(t[c4 + 2][r]);
  h[3] = (short)f2bf(t[c4 + 3][r]);
  *(s16x4*)(o + (size_t)(n0 + r) * FF + k0 + c4) = h;
}

// ---------------------------------------------------------------------------
// Kernel 2: GEMM (m97 structure) + XCD-swizzled linear grid for A-slab L2 reuse.
//   Linear 1536 blocks: wg = (orig&7)*192 + orig>>3 (bijective, 8 XCDs);
//   decode with (n,z) fastest -> 12 consecutive same-XCD blocks share one A-slab.
// ---------------------------------------------------------------------------
__global__ __launch_bounds__(256, 3) void gemm_qkv(
    const unsigned short* __restrict__ xb, const unsigned short* __restrict__ wt,
    const float* __restrict__ bq, const float* __restrict__ bk, const float* __restrict__ bv,
    unsigned short* __restrict__ qo, unsigned short* __restrict__ ko,
    unsigned short* __restrict__ vto) {
  const int orig = blockIdx.x;
  const int wg = (orig & 7) * 192 + (orig >> 3);   // XCD-chunked remap (1536 % 8 == 0)
  const int mt = wg / 12;
  const int r12 = wg - mt * 12;
  const int n0 = (r12 & 3) * 128;
  const int wsel = r12 >> 2;
  const int m0 = mt * 128;

  const unsigned short* W = wt + (size_t)wsel * DD * FF;
  const float* bias = (wsel == 0) ? bq : ((wsel == 1) ? bk : bv);

  __shared__ __align__(16) char smem[36864];
  unsigned short* Al = (unsigned short*)smem;
  unsigned short* Bl = (unsigned short*)(smem + 8192);

  const int tid = threadIdx.x;
  const int lane = tid & 63, wv = tid >> 6;
  const int wr = wv >> 1, wc = wv & 1;
  const int l15 = lane & 15, lg = lane >> 4;

  const f32x4 fzero = {0.f, 0.f, 0.f, 0.f};
  f32x4 acc[4][4];
#pragma unroll
  for (int i = 0; i < 4; ++i)
#pragma unroll
    for (int j = 0; j < 4; ++j) acc[i][j] = fzero;

  for (int k0 = 0; k0 < FF; k0 += 32) {
#pragma unroll
    for (int is = 0; is < 2; ++is) {
      int chunk = (is * 4 + wv) * 64;
      int lin = (chunk + lane) * 8;
      int r = lin >> 5, c = lin & 31;
      async16(xb + (size_t)(m0 + r) * FF + k0 + c, (char*)Al + (size_t)chunk * 16);
      async16(W + (size_t)(n0 + r) * FF + k0 + c, (char*)Bl + (size_t)chunk * 16);
    }
    __syncthreads();
    s16x8 af[4], bf[4];
#pragma unroll
    for (int mi = 0; mi < 4; ++mi)
      af[mi] = *(const s16x8*)(&Al[(wr * 64 + mi * 16 + l15) * 32 + lg * 8]);
#pragma unroll
    for (int ni = 0; ni < 4; ++ni)
      bf[ni] = *(const s16x8*)(&Bl[(wc * 64 + ni * 16 + l15) * 32 + lg * 8]);
#pragma unroll
    for (int mi = 0; mi < 4; ++mi)
#pragma unroll
      for (int ni = 0; ni < 4; ++ni)
        acc[mi][ni] = __builtin_amdgcn_mfma_f32_16x16x32_bf16(af[mi], bf[ni], acc[mi][ni], 0, 0, 0);
    __syncthreads();
  }

  const float QS = 0.0637583894f;  // (1/sqrt(512)) * log2(e)
  if (wsel == 2) {
    unsigned short* Tw = (unsigned short*)smem + (size_t)wv * 64 * 72;
#pragma unroll
    for (int ni = 0; ni < 4; ++ni) {
      int cl = ni * 16 + l15;
      float bvv = bias[n0 + wc * 64 + cl];
#pragma unroll
      for (int mi = 0; mi < 4; ++mi)
#pragma unroll
        for (int j = 0; j < 4; ++j)
          Tw[cl * 72 + mi * 16 + lg * 4 + j] = f2bf(acc[mi][ni][j] + bvv);
    }
    asm volatile("s_waitcnt lgkmcnt(0)" ::: "memory");
    const int bb = (m0 + wr * 64) >> 11;
    const int sb = (m0 + wr * 64) & 2047;
    const int cb = n0 + wc * 64;
#pragma unroll
    for (int p = 0; p < 8; ++p) {
      int cl = p * 8 + (lane >> 3);
      int sl = (lane & 7) * 8;
      s16x8 vv = *(const s16x8*)(Tw + cl * 72 + sl);
      *(s16x8*)(vto + ((size_t)(bb * DD + cb + cl)) * SS + sb + sl) = vv;
    }
  } else {
    unsigned short* o = wsel ? ko : qo;
#pragma unroll
    for (int ni = 0; ni < 4; ++ni) {
      int cg = n0 + wc * 64 + ni * 16 + l15;
      float bvv = bias[cg];
#pragma unroll
      for (int mi = 0; mi < 4; ++mi) {
#pragma unroll
        for (int j = 0; j < 4; ++j) {
          int rg = m0 + wr * 64 + mi * 16 + lg * 4 + j;
          float val = acc[mi][ni][j] + bvv;
          if (wsel == 0) val *= QS;
          o[(size_t)rg * DD + cg] = f2bf(val);
        }
      }
    }
  }
}

// ---------------------------------------------------------------------------
// Kernel 3: causal flash attention.
//   Round-5 structure + (a) XOR-swizzled unpadded K/V LDS -> conflict-free
//   2-way reads AND 54.3KB -> 3 blocks/CU; (b) T13 defer-max (THR=8) skips
//   the O-rescale pass under a wave-uniform vote.
//   K swizzle: col ^= (row&7)<<3   (granule = 8 u16 = 16B, b128-safe)
//   V swizzle: col ^= ((row>>2)&3)<<3
// ---------------------------------------------------------------------------
__global__ __launch_bounds__(256, 3) void attn(const unsigned short* __restrict__ qg,
                                               const unsigned short* __restrict__ kgl,
                                               const unsigned short* __restrict__ vtg,
                                               float* __restrict__ out) {
  const int b = blockIdx.y;
  const int vhalf = blockIdx.z;
  const int qt = (vhalf == 0) ? blockIdx.x : (31 - blockIdx.x);
  const int q0 = qt * 64;

  __shared__ __align__(16) unsigned short Kl[32 * 512];   // 32 KB, swizzled
  __shared__ __align__(16) unsigned short Vl[256 * 32];   // 16 KB, swizzled
  __shared__ __align__(16) unsigned short Pl[4 * 16 * 40];// 5 KB per-wave P bounce

  const int tid = threadIdx.x;
  const int lane = tid & 63, w = tid >> 6;
  const int l15 = lane & 15, lg = lane >> 4;

  // staging geometry
  const int kR = tid >> 6, kC = (tid & 63) * 8;
  const int vN = tid >> 2, vC = (tid & 3) * 8;
  const int vS = vC ^ (((vN >> 2) & 3) << 3);            // V write swizzle (it-invariant)
  const unsigned short* kbase = kgl + ((size_t)(b * SS + kR)) * DD + kC;
  const unsigned short* vbase = vtg + ((size_t)(b * DD + vhalf * 256 + vN)) * SS + vC;

  // preload Q fragments
  s16x8 qf[16];
  {
    const unsigned short* qp = qg + ((size_t)(b * SS + q0 + w * 16 + l15)) * DD + lg * 8;
#pragma unroll
    for (int kk = 0; kk < 16; ++kk) qf[kk] = *(const s16x8*)(qp + kk * 32);
  }

  const f32x4 fzero = {0.f, 0.f, 0.f, 0.f};
  f32x4 oacc[16];
#pragma unroll
  for (int n = 0; n < 16; ++n) oacc[n] = fzero;
  float mrun[4], lsum[4];
#pragma unroll
  for (int i = 0; i < 4; ++i) { mrun[i] = -__builtin_inff(); lsum[i] = 0.f; }

  const int nt = qt * 2 + 2;

  // prefetch tile 0
  f32x4 kreg[8], vreg[4];
#pragma unroll
  for (int it = 0; it < 8; ++it)
    kreg[it] = *(const f32x4*)(kbase + (size_t)(it * 4) * DD);
#pragma unroll
  for (int it = 0; it < 4; ++it)
    vreg[it] = *(const f32x4*)(vbase + (size_t)(it * 64) * SS);

  const int ksw = (l15 & 7) << 3;        // K read swizzle
  const int vsw = ((l15 >> 2) & 3) << 3; // V read swizzle

  for (int t = 0; t < nt; ++t) {
    const int kv0 = t * 32;
    __syncthreads();
    // regs -> LDS, swizzled
#pragma unroll
    for (int it = 0; it < 8; ++it) {
      int row = kR + it * 4;
      *(f32x4*)(&Kl[row * 512 + (kC ^ ((row & 7) << 3))]) = kreg[it];
    }
#pragma unroll
    for (int it = 0; it < 4; ++it)
      *(f32x4*)(&Vl[(vN + it * 64) * 32 + vS]) = vreg[it];
    __syncthreads();

    // prefetch next tile (latency hides under compute)
    if (t + 1 < nt) {
      const int nkv = kv0 + 32;
#pragma unroll
      for (int it = 0; it < 8; ++it)
        kreg[it] = *(const f32x4*)(kbase + (size_t)(nkv + it * 4) * DD);
#pragma unroll
      for (int it = 0; it < 4; ++it)
        vreg[it] = *(const f32x4*)(vbase + (size_t)(it * 64) * SS + nkv);
    }

    // ---- S = Q @ K^T
    f32x4 s0 = fzero, s1 = fzero;
#pragma unroll
    for (int kk = 0; kk < 16; ++kk) {
      s16x8 b0 = *(const s16x8*)(&Kl[l15 * 512 + ((kk * 32 + lg * 8) ^ ksw)]);
      s16x8 b1 = *(const s16x8*)(&Kl[(16 + l15) * 512 + ((kk * 32 + lg * 8) ^ ksw)]);
      s0 = __builtin_amdgcn_mfma_f32_16x16x32_bf16(qf[kk], b0, s0, 0, 0, 0);
      s1 = __builtin_amdgcn_mfma_f32_16x16x32_bf16(qf[kk], b1, s1, 0, 0, 0);
    }

    // ---- causal mask
    const int rowb = q0 + w * 16 + lg * 4;
    if (kv0 + 31 > q0 + w * 16) {
#pragma unroll
      for (int i = 0; i < 4; ++i) {
        int rg = rowb + i;
        if (kv0 + l15 > rg)      s0[i] = -__builtin_inff();
        if (kv0 + 16 + l15 > rg) s1[i] = -__builtin_inff();
      }
    }

    // ---- online softmax with defer-max (THR=8)
    float corr[4];
    int needr = 0;
#pragma unroll
    for (int i = 0; i < 4; ++i) {
      float tm = fmaxf(s0[i], s1[i]);
      tm = fmaxf(tm, __shfl_xor(tm, 1));
      tm = fmaxf(tm, __shfl_xor(tm, 2));
      tm = fmaxf(tm, __shfl_xor(tm, 4));
      tm = fmaxf(tm, __shfl_xor(tm, 8));
      float mo = mrun[i];
      bool upd = (tm > mo + 8.0f);
      float mn = upd ? tm : mo;
      mrun[i] = mn;
      float c = upd ? __builtin_amdgcn_exp2f(mo - mn) : 1.0f;
      float p0 = __builtin_amdgcn_exp2f(s0[i] - mn);
      float p1 = __builtin_amdgcn_exp2f(s1[i] - mn);
      lsum[i] = lsum[i] * c + p0 + p1;
      corr[i] = c;
      needr |= (int)upd;
      Pl[w * 640 + (lg * 4 + i) * 40 + l15] = f2bf(p0);
      Pl[w * 640 + (lg * 4 + i) * 40 + 16 + l15] = f2bf(p1);
    }

    // ---- rescale O only when some row's max moved (wave-uniform vote)
    if (__any(needr)) {
#pragma unroll
      for (int n = 0; n < 16; ++n) {
        oacc[n][0] *= corr[0]; oacc[n][1] *= corr[1];
        oacc[n][2] *= corr[2]; oacc[n][3] *= corr[3];
      }
    }

    // ---- PV: O += P @ V
    asm volatile("s_waitcnt lgkmcnt(0)" ::: "memory");
    s16x8 pa = *(const s16x8*)(&Pl[w * 640 + l15 * 40 + lg * 8]);
#pragma unroll
    for (int n = 0; n < 16; ++n) {
      s16x8 vv = *(const s16x8*)(&Vl[(n * 16 + l15) * 32 + (lg * 8 ^ vsw)]);
      oacc[n] = __builtin_amdgcn_mfma_f32_16x16x32_bf16(pa, vv, oacc[n], 0, 0, 0);
    }
  }

  // ---- epilogue
  float inv[4];
#pragma unroll
  for (int i = 0; i < 4; ++i) {
    float rs = lsum[i];
    rs += __shfl_xor(rs, 1);
    rs += __shfl_xor(rs, 2);
    rs += __shfl_xor(rs, 4);
    rs += __shfl_xor(rs, 8);
    inv[i] = 1.0f / rs;
  }
  size_t obase = ((size_t)(b * SS + q0 + w * 16 + lg * 4)) * 1536 + 1024 + vhalf * 256;
#pragma unroll
  for (int n = 0; n < 16; ++n) {
#pragma unroll
    for (int i = 0; i < 4; ++i) {
      out[obase + (size_t)i * 1536 + n * 16 + l15] = oacc[n][i] * inv[i];
    }
  }
}

// ---------------------------------------------------------------------------
// launch
// ---------------------------------------------------------------------------
extern "C" void kernel_launch(void* const* d_in, const int* in_sizes, int n_in,
                              void* d_out, int out_size, void* d_ws, size_t ws_size,
                              hipStream_t stream) {
  (void)in_sizes; (void)n_in; (void)out_size; (void)ws_size;
  const float* x  = (const float*)d_in[0];
  const float* Wq = (const float*)d_in[1];
  const float* bq = (const float*)d_in[2];
  const float* Wk = (const float*)d_in[3];
  const float* bk = (const float*)d_in[4];
  const float* Wv = (const float*)d_in[5];
  const float* bv = (const float*)d_in[6];
  float* out = (float*)d_out;

  char* ws = (char*)d_ws;
  unsigned short* xb  = (unsigned short*)(ws);                       // 32 MiB
  unsigned short* wt  = (unsigned short*)(ws + 33554432);            // 3 MiB
  unsigned short* qw  = (unsigned short*)(ws + 33554432 + 3145728);  // 16 MiB
  unsigned short* kw  = qw + (size_t)16384 * 512;                    // 16 MiB
  unsigned short* vtw = kw + (size_t)16384 * 512;                    // 16 MiB ([B][512][S])

  convert_x<<<16384, 256, 0, stream>>>(x, out, xb);
  prep_w<<<dim3(32, 16, 3), 256, 0, stream>>>(Wq, Wk, Wv, wt);
  gemm_qkv<<<1536, 256, 0, stream>>>(xb, wt, bq, bk, bv, qw, kw, vtw);
  attn<<<dim3(32, 8, 2), 256, 0, stream>>>(qw, kw, vtw, out);
}

// Round 7
// 381.733 us; speedup vs baseline: 2.1140x; 2.1140x over previous
//
#include <hip/hip_runtime.h>

// Shapes (fixed by the problem)
#define BB 8
#define SS 2048
#define FF 1024
#define DD 512

typedef __attribute__((ext_vector_type(4))) float f32x4;
typedef __attribute__((ext_vector_type(8))) short s16x8;
typedef __attribute__((ext_vector_type(4))) short s16x4;

__device__ __forceinline__ unsigned short f2bf(float f) {
  unsigned int u = __builtin_bit_cast(unsigned int, f);
  unsigned int r = ((u >> 16) & 1u) + 0x7fffu;
  return (unsigned short)((u + r) >> 16);
}

__device__ __forceinline__ void async16(const void* g, void* l) {
  __builtin_amdgcn_global_load_lds((const __attribute__((address_space(1))) void*)g,
                                   (__attribute__((address_space(3))) void*)l, 16, 0, 0);
}

// ---------------------------------------------------------------------------
// Kernel 0: x fp32 -> bf16 (for MFMA) + passthrough copy into out[:, :1024]
// ---------------------------------------------------------------------------
__global__ __launch_bounds__(256) void convert_x(const float* __restrict__ x,
                                                 float* __restrict__ out,
                                                 unsigned short* __restrict__ xb) {
  size_t idx = ((size_t)blockIdx.x * 256 + threadIdx.x) * 4;
  f32x4 v = *(const f32x4*)(x + idx);
  size_t row = idx >> 10;
  size_t col = idx & 1023;
  *(f32x4*)(out + row * 1536 + col) = v;
  s16x4 h;
  h[0] = (short)f2bf(v[0]); h[1] = (short)f2bf(v[1]);
  h[2] = (short)f2bf(v[2]); h[3] = (short)f2bf(v[3]);
  *(s16x4*)(xb + idx) = h;
}

// ---------------------------------------------------------------------------
// Kernel 1: transpose+convert the 3 weights [1024][512] f32 -> Wt bf16 [512][1024]
// ---------------------------------------------------------------------------
__global__ __launch_bounds__(256) void prep_w(const float* __restrict__ Wq,
                                              const float* __restrict__ Wk,
                                              const float* __restrict__ Wv,
                                              unsigned short* __restrict__ wt) {
  int z = blockIdx.z;
  const float* W = (z == 0) ? Wq : ((z == 1) ? Wk : Wv);
  unsigned short* o = wt + (size_t)z * DD * FF;
  __shared__ __align__(16) float t[32][33];
  int k0 = blockIdx.x * 32, n0 = blockIdx.y * 32;
  int tid = threadIdx.x;
  int r = tid >> 3, c4 = (tid & 7) * 4;
  f32x4 v = *(const f32x4*)(W + (size_t)(k0 + r) * DD + n0 + c4);
  t[r][c4 + 0] = v[0]; t[r][c4 + 1] = v[1]; t[r][c4 + 2] = v[2]; t[r][c4 + 3] = v[3];
  __syncthreads();
  s16x4 h;
  h[0] = (short)f2bf(t[c4 + 0][r]);
  h[1] = (short)f2bf(t[c4 + 1][r]);
  h[2] = (short)f2bf(t[c4 + 2][r]);
  h[3] = (short)f2bf(t[c4 + 3][r]);
  *(s16x4*)(o + (size_t)(n0 + r) * FF + k0 + c4) = h;
}

// ---------------------------------------------------------------------------
// Kernel 2: GEMM (m97 structure) + XCD-swizzled linear grid for A-slab L2 reuse.
//   Linear 1536 blocks: wg = (orig&7)*192 + orig>>3 (bijective, 8 XCDs);
//   decode with (n,z) fastest -> 12 consecutive same-XCD blocks share one A-slab.
// ---------------------------------------------------------------------------
__global__ __launch_bounds__(256, 3) void gemm_qkv(
    const unsigned short* __restrict__ xb, const unsigned short* __restrict__ wt,
    const float* __restrict__ bq, const float* __restrict__ bk, const float* __restrict__ bv,
    unsigned short* __restrict__ qo, unsigned short* __restrict__ ko,
    unsigned short* __restrict__ vto) {
  const int orig = blockIdx.x;
  const int wg = (orig & 7) * 192 + (orig >> 3);   // XCD-chunked remap (1536 % 8 == 0)
  const int mt = wg / 12;
  const int r12 = wg - mt * 12;
  const int n0 = (r12 & 3) * 128;
  const int wsel = r12 >> 2;
  const int m0 = mt * 128;

  const unsigned short* W = wt + (size_t)wsel * DD * FF;
  const float* bias = (wsel == 0) ? bq : ((wsel == 1) ? bk : bv);

  __shared__ __align__(16) char smem[36864];
  unsigned short* Al = (unsigned short*)smem;
  unsigned short* Bl = (unsigned short*)(smem + 8192);

  const int tid = threadIdx.x;
  const int lane = tid & 63, wv = tid >> 6;
  const int wr = wv >> 1, wc = wv & 1;
  const int l15 = lane & 15, lg = lane >> 4;

  const f32x4 fzero = {0.f, 0.f, 0.f, 0.f};
  f32x4 acc[4][4];
#pragma unroll
  for (int i = 0; i < 4; ++i)
#pragma unroll
    for (int j = 0; j < 4; ++j) acc[i][j] = fzero;

  for (int k0 = 0; k0 < FF; k0 += 32) {
#pragma unroll
    for (int is = 0; is < 2; ++is) {
      int chunk = (is * 4 + wv) * 64;
      int lin = (chunk + lane) * 8;
      int r = lin >> 5, c = lin & 31;
      async16(xb + (size_t)(m0 + r) * FF + k0 + c, (char*)Al + (size_t)chunk * 16);
      async16(W + (size_t)(n0 + r) * FF + k0 + c, (char*)Bl + (size_t)chunk * 16);
    }
    __syncthreads();
    s16x8 af[4], bf[4];
#pragma unroll
    for (int mi = 0; mi < 4; ++mi)
      af[mi] = *(const s16x8*)(&Al[(wr * 64 + mi * 16 + l15) * 32 + lg * 8]);
#pragma unroll
    for (int ni = 0; ni < 4; ++ni)
      bf[ni] = *(const s16x8*)(&Bl[(wc * 64 + ni * 16 + l15) * 32 + lg * 8]);
#pragma unroll
    for (int mi = 0; mi < 4; ++mi)
#pragma unroll
      for (int ni = 0; ni < 4; ++ni)
        acc[mi][ni] = __builtin_amdgcn_mfma_f32_16x16x32_bf16(af[mi], bf[ni], acc[mi][ni], 0, 0, 0);
    __syncthreads();
  }

  const float QS = 0.0637583894f;  // (1/sqrt(512)) * log2(e)
  if (wsel == 2) {
    unsigned short* Tw = (unsigned short*)smem + (size_t)wv * 64 * 72;
#pragma unroll
    for (int ni = 0; ni < 4; ++ni) {
      int cl = ni * 16 + l15;
      float bvv = bias[n0 + wc * 64 + cl];
#pragma unroll
      for (int mi = 0; mi < 4; ++mi)
#pragma unroll
        for (int j = 0; j < 4; ++j)
          Tw[cl * 72 + mi * 16 + lg * 4 + j] = f2bf(acc[mi][ni][j] + bvv);
    }
    asm volatile("s_waitcnt lgkmcnt(0)" ::: "memory");
    const int bb = (m0 + wr * 64) >> 11;
    const int sb = (m0 + wr * 64) & 2047;
    const int cb = n0 + wc * 64;
#pragma unroll
    for (int p = 0; p < 8; ++p) {
      int cl = p * 8 + (lane >> 3);
      int sl = (lane & 7) * 8;
      s16x8 vv = *(const s16x8*)(Tw + cl * 72 + sl);
      *(s16x8*)(vto + ((size_t)(bb * DD + cb + cl)) * SS + sb + sl) = vv;
    }
  } else {
    unsigned short* o = wsel ? ko : qo;
#pragma unroll
    for (int ni = 0; ni < 4; ++ni) {
      int cg = n0 + wc * 64 + ni * 16 + l15;
      float bvv = bias[cg];
#pragma unroll
      for (int mi = 0; mi < 4; ++mi) {
#pragma unroll
        for (int j = 0; j < 4; ++j) {
          int rg = m0 + wr * 64 + mi * 16 + lg * 4 + j;
          float val = acc[mi][ni][j] + bvv;
          if (wsel == 0) val *= QS;
          o[(size_t)rg * DD + cg] = f2bf(val);
        }
      }
    }
  }
}

// ---------------------------------------------------------------------------
// Kernel 3: causal flash attention.
//   Round-5 structure + swizzled unpadded K/V LDS (54,272 B -> 3 blocks/CU by
//   LDS) + defer-max. launch_bounds (256,2): do NOT squeeze the allocator —
//   compiler uses ~120 VGPR naturally (4 waves/SIMD allowed), runtime
//   occupancy = 3 blocks/CU via LDS. (256,3) forced spills: 84 VGPR +
//   1.3 GB/dispatch scratch traffic (round-6 post-mortem).
//   K swizzle: col ^= (row&7)<<3; V swizzle: col ^= ((row>>2)&3)<<3.
// ---------------------------------------------------------------------------
__global__ __launch_bounds__(256, 2) void attn(const unsigned short* __restrict__ qg,
                                               const unsigned short* __restrict__ kgl,
                                               const unsigned short* __restrict__ vtg,
                                               float* __restrict__ out) {
  const int b = blockIdx.y;
  const int vhalf = blockIdx.z;
  const int qt = (vhalf == 0) ? blockIdx.x : (31 - blockIdx.x);
  const int q0 = qt * 64;

  __shared__ __align__(16) unsigned short Kl[32 * 512];   // 32 KB, swizzled
  __shared__ __align__(16) unsigned short Vl[256 * 32];   // 16 KB, swizzled
  __shared__ __align__(16) unsigned short Pl[4 * 16 * 40];// 5 KB per-wave P bounce

  const int tid = threadIdx.x;
  const int lane = tid & 63, w = tid >> 6;
  const int l15 = lane & 15, lg = lane >> 4;

  // staging geometry
  const int kR = tid >> 6, kC = (tid & 63) * 8;
  const int vN = tid >> 2, vC = (tid & 3) * 8;
  const int vS = vC ^ (((vN >> 2) & 3) << 3);            // V write swizzle (it-invariant)
  const unsigned short* kbase = kgl + ((size_t)(b * SS + kR)) * DD + kC;
  const unsigned short* vbase = vtg + ((size_t)(b * DD + vhalf * 256 + vN)) * SS + vC;

  // preload Q fragments
  s16x8 qf[16];
  {
    const unsigned short* qp = qg + ((size_t)(b * SS + q0 + w * 16 + l15)) * DD + lg * 8;
#pragma unroll
    for (int kk = 0; kk < 16; ++kk) qf[kk] = *(const s16x8*)(qp + kk * 32);
  }

  const f32x4 fzero = {0.f, 0.f, 0.f, 0.f};
  f32x4 oacc[16];
#pragma unroll
  for (int n = 0; n < 16; ++n) oacc[n] = fzero;
  float mrun[4], lsum[4];
#pragma unroll
  for (int i = 0; i < 4; ++i) { mrun[i] = -__builtin_inff(); lsum[i] = 0.f; }

  const int nt = qt * 2 + 2;

  // prefetch tile 0
  f32x4 kreg[8], vreg[4];
#pragma unroll
  for (int it = 0; it < 8; ++it)
    kreg[it] = *(const f32x4*)(kbase + (size_t)(it * 4) * DD);
#pragma unroll
  for (int it = 0; it < 4; ++it)
    vreg[it] = *(const f32x4*)(vbase + (size_t)(it * 64) * SS);

  const int ksw = (l15 & 7) << 3;        // K read swizzle
  const int vsw = ((l15 >> 2) & 3) << 3; // V read swizzle

  for (int t = 0; t < nt; ++t) {
    const int kv0 = t * 32;
    __syncthreads();
    // regs -> LDS, swizzled
#pragma unroll
    for (int it = 0; it < 8; ++it) {
      int row = kR + it * 4;
      *(f32x4*)(&Kl[row * 512 + (kC ^ ((row & 7) << 3))]) = kreg[it];
    }
#pragma unroll
    for (int it = 0; it < 4; ++it)
      *(f32x4*)(&Vl[(vN + it * 64) * 32 + vS]) = vreg[it];
    __syncthreads();

    // prefetch next tile (latency hides under compute)
    if (t + 1 < nt) {
      const int nkv = kv0 + 32;
#pragma unroll
      for (int it = 0; it < 8; ++it)
        kreg[it] = *(const f32x4*)(kbase + (size_t)(nkv + it * 4) * DD);
#pragma unroll
      for (int it = 0; it < 4; ++it)
        vreg[it] = *(const f32x4*)(vbase + (size_t)(it * 64) * SS + nkv);
    }

    // ---- S = Q @ K^T
    f32x4 s0 = fzero, s1 = fzero;
#pragma unroll
    for (int kk = 0; kk < 16; ++kk) {
      s16x8 b0 = *(const s16x8*)(&Kl[l15 * 512 + ((kk * 32 + lg * 8) ^ ksw)]);
      s16x8 b1 = *(const s16x8*)(&Kl[(16 + l15) * 512 + ((kk * 32 + lg * 8) ^ ksw)]);
      s0 = __builtin_amdgcn_mfma_f32_16x16x32_bf16(qf[kk], b0, s0, 0, 0, 0);
      s1 = __builtin_amdgcn_mfma_f32_16x16x32_bf16(qf[kk], b1, s1, 0, 0, 0);
    }

    // ---- causal mask
    const int rowb = q0 + w * 16 + lg * 4;
    if (kv0 + 31 > q0 + w * 16) {
#pragma unroll
      for (int i = 0; i < 4; ++i) {
        int rg = rowb + i;
        if (kv0 + l15 > rg)      s0[i] = -__builtin_inff();
        if (kv0 + 16 + l15 > rg) s1[i] = -__builtin_inff();
      }
    }

    // ---- online softmax with defer-max (THR=8)
    float corr[4];
    int needr = 0;
#pragma unroll
    for (int i = 0; i < 4; ++i) {
      float tm = fmaxf(s0[i], s1[i]);
      tm = fmaxf(tm, __shfl_xor(tm, 1));
      tm = fmaxf(tm, __shfl_xor(tm, 2));
      tm = fmaxf(tm, __shfl_xor(tm, 4));
      tm = fmaxf(tm, __shfl_xor(tm, 8));
      float mo = mrun[i];
      bool upd = (tm > mo + 8.0f);
      float mn = upd ? tm : mo;
      mrun[i] = mn;
      float c = upd ? __builtin_amdgcn_exp2f(mo - mn) : 1.0f;
      float p0 = __builtin_amdgcn_exp2f(s0[i] - mn);
      float p1 = __builtin_amdgcn_exp2f(s1[i] - mn);
      lsum[i] = lsum[i] * c + p0 + p1;
      corr[i] = c;
      needr |= (int)upd;
      Pl[w * 640 + (lg * 4 + i) * 40 + l15] = f2bf(p0);
      Pl[w * 640 + (lg * 4 + i) * 40 + 16 + l15] = f2bf(p1);
    }

    // ---- rescale O only when some row's max moved (wave-uniform vote)
    if (__any(needr)) {
#pragma unroll
      for (int n = 0; n < 16; ++n) {
        oacc[n][0] *= corr[0]; oacc[n][1] *= corr[1];
        oacc[n][2] *= corr[2]; oacc[n][3] *= corr[3];
      }
    }

    // ---- PV: O += P @ V
    asm volatile("s_waitcnt lgkmcnt(0)" ::: "memory");
    s16x8 pa = *(const s16x8*)(&Pl[w * 640 + l15 * 40 + lg * 8]);
#pragma unroll
    for (int n = 0; n < 16; ++n) {
      s16x8 vv = *(const s16x8*)(&Vl[(n * 16 + l15) * 32 + (lg * 8 ^ vsw)]);
      oacc[n] = __builtin_amdgcn_mfma_f32_16x16x32_bf16(pa, vv, oacc[n], 0, 0, 0);
    }
  }

  // ---- epilogue
  float inv[4];
#pragma unroll
  for (int i = 0; i < 4; ++i) {
    float rs = lsum[i];
    rs += __shfl_xor(rs, 1);
    rs += __shfl_xor(rs, 2);
    rs += __shfl_xor(rs, 4);
    rs += __shfl_xor(rs, 8);
    inv[i] = 1.0f / rs;
  }
  size_t obase = ((size_t)(b * SS + q0 + w * 16 + lg * 4)) * 1536 + 1024 + vhalf * 256;
#pragma unroll
  for (int n = 0; n < 16; ++n) {
#pragma unroll
    for (int i = 0; i < 4; ++i) {
      out[obase + (size_t)i * 1536 + n * 16 + l15] = oacc[n][i] * inv[i];
    }
  }
}

// ---------------------------------------------------------------------------
// launch
// ---------------------------------------------------------------------------
extern "C" void kernel_launch(void* const* d_in, const int* in_sizes, int n_in,
                              void* d_out, int out_size, void* d_ws, size_t ws_size,
                              hipStream_t stream) {
  (void)in_sizes; (void)n_in; (void)out_size; (void)ws_size;
  const float* x  = (const float*)d_in[0];
  const float* Wq = (const float*)d_in[1];
  const float* bq = (const float*)d_in[2];
  const float* Wk = (const float*)d_in[3];
  const float* bk = (const float*)d_in[4];
  const float* Wv = (const float*)d_in[5];
  const float* bv = (const float*)d_in[6];
  float* out = (float*)d_out;

  char* ws = (char*)d_ws;
  unsigned short* xb  = (unsigned short*)(ws);                       // 32 MiB
  unsigned short* wt  = (unsigned short*)(ws + 33554432);            // 3 MiB
  unsigned short* qw  = (unsigned short*)(ws + 33554432 + 3145728);  // 16 MiB
  unsigned short* kw  = qw + (size_t)16384 * 512;                    // 16 MiB
  unsigned short* vtw = kw + (size_t)16384 * 512;                    // 16 MiB ([B][512][S])

  convert_x<<<16384, 256, 0, stream>>>(x, out, xb);
  prep_w<<<dim3(32, 16, 3), 256, 0, stream>>>(Wq, Wk, Wv, wt);
  gemm_qkv<<<1536, 256, 0, stream>>>(xb, wt, bq, bk, bv, qw, kw, vtw);
  attn<<<dim3(32, 8, 2), 256, 0, stream>>>(qw, kw, vtw, out);
}